// Round 1
// baseline (1318.220 us; speedup 1.0000x reference)
//
#include <hip/hip_runtime.h>
#include <hip/hip_bf16.h>

// Sparse 3D conv block (4x 27-tap convs, N=64), float32 in/out.
// Round 5: MT=256 tile, wave tile 64x64 (Mt=2 x Nt=2) -> reads/MFMA 1.0 -> 0.67,
//          T14 async-STAGE split (load tap k+1 to regs before computing tap k).
//   - split-bf16 emulated f32 (hi*hi + hi*lo + lo*hi), numerics unchanged
//   - unified 256B LDS rows: 16 slots of 16B; hi slots 0-7, lo slots 8-15,
//     slot = (g ^ (row&7)) + 8*half  (read-side XOR swizzle unchanged)
//   - staging slot rotation s=(c+row)&15 (A) / s=(m+4q+row)&15 (B): each
//     wave-instruction touches all 32 banks uniformly (8 dwords/bank = b128 min)
//   - LDS 80KB -> 2 blocks/CU; __launch_bounds__(256,2)

#define N 64
#define TAPS 27
#define MT 256

typedef unsigned short u16;
typedef __attribute__((ext_vector_type(8))) short short8;
typedef __attribute__((ext_vector_type(16))) float floatx16;

__device__ __forceinline__ float bf2f(u16 v) {
    union { unsigned u; float f; } c;
    c.u = ((unsigned)v) << 16;
    return c.f;
}
__device__ __forceinline__ u16 f2bf(float f) {
    __hip_bfloat16 h = __float2bfloat16(f);  // RNE
    u16 r;
    __builtin_memcpy(&r, &h, 2);
    return r;
}
__device__ __forceinline__ void split2(float x, u16& hi, u16& lo) {
    hi = f2bf(x);
    lo = f2bf(x - bf2f(hi));
}

// feats f32 [P][64] -> hl bf16 [P][128] (row = hi[0:64] || lo[64:128])
__global__ void split_feats(const float* __restrict__ x, u16* __restrict__ hl, int n) {
    int i = blockIdx.x * 256 + threadIdx.x;
    if (i >= n) return;
    int p = i >> 6, c = i & 63;
    u16 h, l;
    split2(x[i], h, l);
    hl[(size_t)p * 128 + c] = h;
    hl[(size_t)p * 128 + 64 + c] = l;
}

// W f32 [27][64][64] (k,i,j) -> Wt bf16 [27][64][128] (k, j, i_hi||i_lo)
__global__ void transpose_w(const float* __restrict__ W, u16* __restrict__ Wt) {
    const float* src = W + blockIdx.x * (N * N);
    u16* dst = Wt + blockIdx.x * (N * 128);
    int t = threadIdx.x;
#pragma unroll
    for (int m = 0; m < 16; ++m) {
        int e = t + m * 256;
        int i = e >> 6;
        int j = e & 63;
        u16 h, l;
        split2(src[e], h, l);
        dst[j * 128 + i] = h;
        dst[j * 128 + 64 + i] = l;
    }
}

// MODE: 0/2 = relu -> hl out; 1 = FiLM -> hl out; 3 = relu + residual -> f32 out
template <int MODE>
__global__ __launch_bounds__(256, 2) void conv_k(
    const u16* __restrict__ Xhl, const u16* __restrict__ Wt,
    const float* __restrict__ bias, const int* __restrict__ nbr,
    const float* __restrict__ cond, const float* __restrict__ resid,
    u16* __restrict__ out_hl, float* __restrict__ out_f32, int P) {
    __shared__ __align__(16) u16 As[MT * 128];  // 64 KB: 256 rows x 16 swizzled 16B slots
    __shared__ __align__(16) u16 Bs[N * 128];   // 16 KB: 64 rows x 16 swizzled 16B slots

    const int tid = threadIdx.x;
    const int pbase = blockIdx.x * MT;

    // staging roles: one A row per thread; B row per 4 threads
    const int tA = tid;
    const int prA = pbase + tA;
    const long nbrbase = (long)prA * TAPS;
    const int rB = tid >> 2;
    const int mB = tid & 3;

    // compute roles: wave w -> rows [w*64, w*64+64) x all 64 cols
    const int w = tid >> 6;
    const int lane = tid & 63;
    const int cn = lane & 31;     // m-row / n-col within 32x32 tile
    const int kh = lane >> 5;     // K half (8-elem group)
    const int rowA0 = w * 64 + cn;

    floatx16 acc00, acc01, acc10, acc11;
#pragma unroll
    for (int i = 0; i < 16; ++i) { acc00[i] = 0.f; acc01[i] = 0.f; acc10[i] = 0.f; acc11[i] = 0.f; }

    uint4 ra[16];   // prefetched A row (16 slots in staged order)
    uint4 rb[4];    // prefetched B slots

    int idxN = (prA < P) ? nbr[nbrbase] : -1;   // neighbor idx for next tap to load

    const u16* wtap = Wt + (size_t)rB * 128;

    // load tap kload's data into registers (uses idxN == nbr[., kload])
    auto load_regs = [&](int kload) {
        const bool valid = (idxN >= 0);
        const size_t xb = (size_t)(valid ? idxN : 0) * 128;
#pragma unroll
        for (int c = 0; c < 16; ++c) {
            const int s = (c + tA) & 15;                             // dest slot
            const int src = (s >> 3) * 64 + (((s & 7) ^ (tA & 7)) * 8);  // logical granule
            uint4 v = make_uint4(0u, 0u, 0u, 0u);
            if (valid) v = *reinterpret_cast<const uint4*>(Xhl + xb + src);
            ra[c] = v;
        }
        const u16* wrow = wtap + (size_t)kload * (N * 128);
#pragma unroll
        for (int q = 0; q < 4; ++q) {
            const int s = (mB + 4 * q + rB) & 15;
            const int src = (s >> 3) * 64 + (((s & 7) ^ (rB & 7)) * 8);
            rb[q] = *reinterpret_cast<const uint4*>(wrow + src);
        }
        idxN = (kload + 1 < TAPS && prA < P) ? nbr[nbrbase + kload + 1] : -1;
    };

    auto write_lds = [&]() {
#pragma unroll
        for (int c = 0; c < 16; ++c) {
            const int s = (c + tA) & 15;
            *reinterpret_cast<uint4*>(&As[tA * 128 + s * 8]) = ra[c];
        }
#pragma unroll
        for (int q = 0; q < 4; ++q) {
            const int s = (mB + 4 * q + rB) & 15;
            *reinterpret_cast<uint4*>(&Bs[rB * 128 + s * 8]) = rb[q];
        }
    };

    load_regs(0);
    write_lds();
    __syncthreads();

    for (int k = 0; k < TAPS; ++k) {
        // issue next tap's global loads now; they retire under this tap's compute
        if (k + 1 < TAPS) load_regs(k + 1);

        // ---- compute tap k: 4 K-chunks, 2x2 MFMA tiles, 3 emulation products
#pragma unroll
        for (int kc = 0; kc < 4; ++kc) {
            const int g = 2 * kc + kh;
            const int sw = (g ^ (cn & 7)) * 8;
            const short8 a_h0 = *reinterpret_cast<const short8*>(&As[rowA0 * 128 + sw]);
            const short8 a_l0 = *reinterpret_cast<const short8*>(&As[rowA0 * 128 + 64 + sw]);
            const short8 a_h1 = *reinterpret_cast<const short8*>(&As[(rowA0 + 32) * 128 + sw]);
            const short8 a_l1 = *reinterpret_cast<const short8*>(&As[(rowA0 + 32) * 128 + 64 + sw]);
            const short8 b_h0 = *reinterpret_cast<const short8*>(&Bs[cn * 128 + sw]);
            const short8 b_l0 = *reinterpret_cast<const short8*>(&Bs[cn * 128 + 64 + sw]);
            const short8 b_h1 = *reinterpret_cast<const short8*>(&Bs[(cn + 32) * 128 + sw]);
            const short8 b_l1 = *reinterpret_cast<const short8*>(&Bs[(cn + 32) * 128 + 64 + sw]);

            acc00 = __builtin_amdgcn_mfma_f32_32x32x16_bf16(a_h0, b_h0, acc00, 0, 0, 0);
            acc00 = __builtin_amdgcn_mfma_f32_32x32x16_bf16(a_h0, b_l0, acc00, 0, 0, 0);
            acc00 = __builtin_amdgcn_mfma_f32_32x32x16_bf16(a_l0, b_h0, acc00, 0, 0, 0);

            acc01 = __builtin_amdgcn_mfma_f32_32x32x16_bf16(a_h0, b_h1, acc01, 0, 0, 0);
            acc01 = __builtin_amdgcn_mfma_f32_32x32x16_bf16(a_h0, b_l1, acc01, 0, 0, 0);
            acc01 = __builtin_amdgcn_mfma_f32_32x32x16_bf16(a_l0, b_h1, acc01, 0, 0, 0);

            acc10 = __builtin_amdgcn_mfma_f32_32x32x16_bf16(a_h1, b_h0, acc10, 0, 0, 0);
            acc10 = __builtin_amdgcn_mfma_f32_32x32x16_bf16(a_h1, b_l0, acc10, 0, 0, 0);
            acc10 = __builtin_amdgcn_mfma_f32_32x32x16_bf16(a_l1, b_h0, acc10, 0, 0, 0);

            acc11 = __builtin_amdgcn_mfma_f32_32x32x16_bf16(a_h1, b_h1, acc11, 0, 0, 0);
            acc11 = __builtin_amdgcn_mfma_f32_32x32x16_bf16(a_h1, b_l1, acc11, 0, 0, 0);
            acc11 = __builtin_amdgcn_mfma_f32_32x32x16_bf16(a_l1, b_h1, acc11, 0, 0, 0);
        }

        __syncthreads();                       // all waves done reading tap k
        if (k + 1 < TAPS) {
            write_lds();                       // prefetched regs -> LDS
            __syncthreads();                   // tap k+1 visible
        }
    }

    // ---- epilogue: 32x32 C/D layout col=lane&31, row=(reg&3)+8*(reg>>2)+4*kh
    auto epi = [&](const floatx16& a, int mt, int nt) {
        const int j = nt * 32 + cn;
        const float bj = bias[j];
#pragma unroll
        for (int reg = 0; reg < 16; ++reg) {
            const int row = (reg & 3) + 8 * (reg >> 2) + 4 * kh;
            const int p = pbase + w * 64 + mt * 32 + row;
            if (p < P) {
                float o = a[reg] + bj;
                if (MODE == 0 || MODE == 2) o = fmaxf(o, 0.f);
                if (MODE == 1) {
                    const float be = cond[(size_t)p * (2 * N) + j];
                    const float ga = cond[(size_t)p * (2 * N) + N + j];
                    o = o * be + ga;
                }
                if (MODE == 3) {
                    o = fmaxf(o, 0.f) + resid[(size_t)p * N + j];
                    out_f32[(size_t)p * N + j] = o;
                } else {
                    u16 h, l;
                    split2(o, h, l);
                    out_hl[(size_t)p * 128 + j] = h;
                    out_hl[(size_t)p * 128 + 64 + j] = l;
                }
            }
        }
    };
    epi(acc00, 0, 0);
    epi(acc01, 0, 1);
    epi(acc10, 1, 0);
    epi(acc11, 1, 1);
}

extern "C" void kernel_launch(void* const* d_in, const int* in_sizes, int n_in,
                              void* d_out, int out_size, void* d_ws, size_t ws_size,
                              hipStream_t stream) {
    const float* feats = (const float*)d_in[0];
    const float* cond  = (const float*)d_in[1];
    const float* W1a   = (const float*)d_in[2];
    const float* b1a   = (const float*)d_in[3];
    const float* W1b   = (const float*)d_in[4];
    const float* b1b   = (const float*)d_in[5];
    const float* W2a   = (const float*)d_in[6];
    const float* b2a   = (const float*)d_in[7];
    const float* W2b   = (const float*)d_in[8];
    const float* b2b   = (const float*)d_in[9];
    const int* nbr     = (const int*)d_in[10];
    float* out = (float*)d_out;
    u16* out_hl = (u16*)d_out;   // d_out doubles as hl scratch (P*128 bf16 == P*64 f32 bytes)

    const int P = in_sizes[0] / N;

    const size_t wtElems = (size_t)TAPS * N * 128;  // 221184 bf16 per conv
    u16* wt0 = (u16*)d_ws;
    u16* wt1 = wt0 + wtElems;
    u16* wt2 = wt1 + wtElems;
    u16* wt3 = wt2 + wtElems;
    u16* hA  = wt3 + wtElems;    // P*128 bf16 intermediate

    transpose_w<<<TAPS, 256, 0, stream>>>(W1a, wt0);
    transpose_w<<<TAPS, 256, 0, stream>>>(W1b, wt1);
    transpose_w<<<TAPS, 256, 0, stream>>>(W2a, wt2);
    transpose_w<<<TAPS, 256, 0, stream>>>(W2b, wt3);
    split_feats<<<(P * N + 255) / 256, 256, 0, stream>>>(feats, out_hl, P * N);

    const int blocks = (P + MT - 1) / MT;
    conv_k<0><<<blocks, 256, 0, stream>>>(out_hl, wt0, b1a, nbr, nullptr, nullptr, hA, nullptr, P);
    conv_k<1><<<blocks, 256, 0, stream>>>(hA, wt1, b1b, nbr, cond, nullptr, out_hl, nullptr, P);
    conv_k<2><<<blocks, 256, 0, stream>>>(out_hl, wt2, b2a, nbr, nullptr, nullptr, hA, nullptr, P);
    conv_k<3><<<blocks, 256, 0, stream>>>(hA, wt3, b2b, nbr, nullptr, feats, nullptr, out, P);
}

// Round 2
// 1261.520 us; speedup vs baseline: 1.0449x; 1.0449x over previous
//
#include <hip/hip_runtime.h>
#include <hip/hip_bf16.h>

// Sparse 3D conv block (4x 27-tap convs, N=64), float32 in/out.
// Round 6: MT=256 tile, wave tile 64x64 (Mt=2 x Nt=2) -> reads/MFMA 0.67,
//          INLINE staging (round-4 discipline: no cross-barrier register arrays;
//          round-5's T14 reg prefetch spilled -> +181MB scratch writes/dispatch).
//   - split-bf16 emulated f32 (hi*hi + hi*lo + lo*hi), numerics unchanged
//   - unified 256B LDS rows: 16 slots of 16B; hi slots 0-7, lo slots 8-15,
//     slot = (g ^ (row&7)) + 8*half  (read-side XOR swizzle)
//   - staging slot rotation s=(c+row)&15 (A) / s=(m+4q+row)&15 (B): each
//     wave-instruction touches all 32 banks uniformly (8 dwords/bank = b128 min)
//   - LDS 80KB -> 2 blocks/CU; __launch_bounds__(256,2)

#define N 64
#define TAPS 27
#define MT 256

typedef unsigned short u16;
typedef __attribute__((ext_vector_type(8))) short short8;
typedef __attribute__((ext_vector_type(16))) float floatx16;

__device__ __forceinline__ float bf2f(u16 v) {
    union { unsigned u; float f; } c;
    c.u = ((unsigned)v) << 16;
    return c.f;
}
__device__ __forceinline__ u16 f2bf(float f) {
    __hip_bfloat16 h = __float2bfloat16(f);  // RNE
    u16 r;
    __builtin_memcpy(&r, &h, 2);
    return r;
}
__device__ __forceinline__ void split2(float x, u16& hi, u16& lo) {
    hi = f2bf(x);
    lo = f2bf(x - bf2f(hi));
}

// feats f32 [P][64] -> hl bf16 [P][128] (row = hi[0:64] || lo[64:128])
__global__ void split_feats(const float* __restrict__ x, u16* __restrict__ hl, int n) {
    int i = blockIdx.x * 256 + threadIdx.x;
    if (i >= n) return;
    int p = i >> 6, c = i & 63;
    u16 h, l;
    split2(x[i], h, l);
    hl[(size_t)p * 128 + c] = h;
    hl[(size_t)p * 128 + 64 + c] = l;
}

// W f32 [27][64][64] (k,i,j) -> Wt bf16 [27][64][128] (k, j, i_hi||i_lo)
__global__ void transpose_w(const float* __restrict__ W, u16* __restrict__ Wt) {
    const float* src = W + blockIdx.x * (N * N);
    u16* dst = Wt + blockIdx.x * (N * 128);
    int t = threadIdx.x;
#pragma unroll
    for (int m = 0; m < 16; ++m) {
        int e = t + m * 256;
        int i = e >> 6;
        int j = e & 63;
        u16 h, l;
        split2(src[e], h, l);
        dst[j * 128 + i] = h;
        dst[j * 128 + 64 + i] = l;
    }
}

// MODE: 0/2 = relu -> hl out; 1 = FiLM -> hl out; 3 = relu + residual -> f32 out
template <int MODE>
__global__ __launch_bounds__(256, 2) void conv_k(
    const u16* __restrict__ Xhl, const u16* __restrict__ Wt,
    const float* __restrict__ bias, const int* __restrict__ nbr,
    const float* __restrict__ cond, const float* __restrict__ resid,
    u16* __restrict__ out_hl, float* __restrict__ out_f32, int P) {
    __shared__ __align__(16) u16 As[MT * 128];  // 64 KB: 256 rows x 16 swizzled 16B slots
    __shared__ __align__(16) u16 Bs[N * 128];   // 16 KB: 64 rows x 16 swizzled 16B slots

    const int tid = threadIdx.x;
    const int pbase = blockIdx.x * MT;

    // staging roles: one A row per thread; B row per 4 threads
    const int tA = tid;
    const int prA = pbase + tA;
    const long nbrbase = (long)prA * TAPS;
    const int rB = tid >> 2;
    const int mB = tid & 3;

    // compute roles: wave w -> rows [w*64, w*64+64) x all 64 cols
    const int w = tid >> 6;
    const int lane = tid & 63;
    const int cn = lane & 31;     // m-row / n-col within 32x32 tile
    const int kh = lane >> 5;     // K half (8-elem group)
    const int rowA0 = w * 64 + cn;

    floatx16 acc00, acc01, acc10, acc11;
#pragma unroll
    for (int i = 0; i < 16; ++i) { acc00[i] = 0.f; acc01[i] = 0.f; acc10[i] = 0.f; acc11[i] = 0.f; }

    int idx = (prA < P) ? nbr[nbrbase] : -1;   // neighbor idx for tap about to stage

    const u16* wtap = Wt + (size_t)rB * 128;

    for (int k = 0; k < TAPS; ++k) {
        if (k) __syncthreads();  // previous tap's frag reads complete

        // ---- stage A: 16 slots of the gathered hl row (zero if missing), inline
        {
            const bool valid = (idx >= 0);
            const u16* xrow = Xhl + (size_t)(valid ? idx : 0) * 128;
#pragma unroll
            for (int c = 0; c < 16; ++c) {
                const int s = (c + tA) & 15;                                  // dest slot
                const int src = (s >> 3) * 64 + (((s & 7) ^ (tA & 7)) * 8);   // logical granule
                uint4 v = make_uint4(0u, 0u, 0u, 0u);
                if (valid) v = *reinterpret_cast<const uint4*>(xrow + src);
                *reinterpret_cast<uint4*>(&As[tA * 128 + s * 8]) = v;
            }
        }
        // ---- stage B: 4 slots of Wt[k], inline
        {
            const u16* wrow = wtap + (size_t)k * (N * 128);
#pragma unroll
            for (int q = 0; q < 4; ++q) {
                const int s = (mB + 4 * q + rB) & 15;
                const int src = (s >> 3) * 64 + (((s & 7) ^ (rB & 7)) * 8);
                *reinterpret_cast<uint4*>(&Bs[rB * 128 + s * 8]) =
                    *reinterpret_cast<const uint4*>(wrow + src);
            }
        }
        // prefetch next tap's neighbor index (single scalar, cheap)
        idx = (k + 1 < TAPS && prA < P) ? nbr[nbrbase + k + 1] : -1;

        __syncthreads();  // staged data visible

        // ---- compute tap k: 4 K-chunks, 2x2 MFMA tiles, 3 emulation products
#pragma unroll
        for (int kc = 0; kc < 4; ++kc) {
            const int g = 2 * kc + kh;
            const int sw = (g ^ (cn & 7)) * 8;
            const short8 a_h0 = *reinterpret_cast<const short8*>(&As[rowA0 * 128 + sw]);
            const short8 a_l0 = *reinterpret_cast<const short8*>(&As[rowA0 * 128 + 64 + sw]);
            const short8 a_h1 = *reinterpret_cast<const short8*>(&As[(rowA0 + 32) * 128 + sw]);
            const short8 a_l1 = *reinterpret_cast<const short8*>(&As[(rowA0 + 32) * 128 + 64 + sw]);
            const short8 b_h0 = *reinterpret_cast<const short8*>(&Bs[cn * 128 + sw]);
            const short8 b_l0 = *reinterpret_cast<const short8*>(&Bs[cn * 128 + 64 + sw]);
            const short8 b_h1 = *reinterpret_cast<const short8*>(&Bs[(cn + 32) * 128 + sw]);
            const short8 b_l1 = *reinterpret_cast<const short8*>(&Bs[(cn + 32) * 128 + 64 + sw]);

            acc00 = __builtin_amdgcn_mfma_f32_32x32x16_bf16(a_h0, b_h0, acc00, 0, 0, 0);
            acc00 = __builtin_amdgcn_mfma_f32_32x32x16_bf16(a_h0, b_l0, acc00, 0, 0, 0);
            acc00 = __builtin_amdgcn_mfma_f32_32x32x16_bf16(a_l0, b_h0, acc00, 0, 0, 0);

            acc01 = __builtin_amdgcn_mfma_f32_32x32x16_bf16(a_h0, b_h1, acc01, 0, 0, 0);
            acc01 = __builtin_amdgcn_mfma_f32_32x32x16_bf16(a_h0, b_l1, acc01, 0, 0, 0);
            acc01 = __builtin_amdgcn_mfma_f32_32x32x16_bf16(a_l0, b_h1, acc01, 0, 0, 0);

            acc10 = __builtin_amdgcn_mfma_f32_32x32x16_bf16(a_h1, b_h0, acc10, 0, 0, 0);
            acc10 = __builtin_amdgcn_mfma_f32_32x32x16_bf16(a_h1, b_l0, acc10, 0, 0, 0);
            acc10 = __builtin_amdgcn_mfma_f32_32x32x16_bf16(a_l1, b_h0, acc10, 0, 0, 0);

            acc11 = __builtin_amdgcn_mfma_f32_32x32x16_bf16(a_h1, b_h1, acc11, 0, 0, 0);
            acc11 = __builtin_amdgcn_mfma_f32_32x32x16_bf16(a_h1, b_l1, acc11, 0, 0, 0);
            acc11 = __builtin_amdgcn_mfma_f32_32x32x16_bf16(a_l1, b_h1, acc11, 0, 0, 0);
        }
    }

    // ---- epilogue: 32x32 C/D layout col=lane&31, row=(reg&3)+8*(reg>>2)+4*kh
    auto epi = [&](const floatx16& a, int mt, int nt) {
        const int j = nt * 32 + cn;
        const float bj = bias[j];
#pragma unroll
        for (int reg = 0; reg < 16; ++reg) {
            const int row = (reg & 3) + 8 * (reg >> 2) + 4 * kh;
            const int p = pbase + w * 64 + mt * 32 + row;
            if (p < P) {
                float o = a[reg] + bj;
                if (MODE == 0 || MODE == 2) o = fmaxf(o, 0.f);
                if (MODE == 1) {
                    const float be = cond[(size_t)p * (2 * N) + j];
                    const float ga = cond[(size_t)p * (2 * N) + N + j];
                    o = o * be + ga;
                }
                if (MODE == 3) {
                    o = fmaxf(o, 0.f) + resid[(size_t)p * N + j];
                    out_f32[(size_t)p * N + j] = o;
                } else {
                    u16 h, l;
                    split2(o, h, l);
                    out_hl[(size_t)p * 128 + j] = h;
                    out_hl[(size_t)p * 128 + 64 + j] = l;
                }
            }
        }
    };
    epi(acc00, 0, 0);
    epi(acc01, 0, 1);
    epi(acc10, 1, 0);
    epi(acc11, 1, 1);
}

extern "C" void kernel_launch(void* const* d_in, const int* in_sizes, int n_in,
                              void* d_out, int out_size, void* d_ws, size_t ws_size,
                              hipStream_t stream) {
    const float* feats = (const float*)d_in[0];
    const float* cond  = (const float*)d_in[1];
    const float* W1a   = (const float*)d_in[2];
    const float* b1a   = (const float*)d_in[3];
    const float* W1b   = (const float*)d_in[4];
    const float* b1b   = (const float*)d_in[5];
    const float* W2a   = (const float*)d_in[6];
    const float* b2a   = (const float*)d_in[7];
    const float* W2b   = (const float*)d_in[8];
    const float* b2b   = (const float*)d_in[9];
    const int* nbr     = (const int*)d_in[10];
    float* out = (float*)d_out;
    u16* out_hl = (u16*)d_out;   // d_out doubles as hl scratch (P*128 bf16 == P*64 f32 bytes)

    const int P = in_sizes[0] / N;

    const size_t wtElems = (size_t)TAPS * N * 128;  // 221184 bf16 per conv
    u16* wt0 = (u16*)d_ws;
    u16* wt1 = wt0 + wtElems;
    u16* wt2 = wt1 + wtElems;
    u16* wt3 = wt2 + wtElems;
    u16* hA  = wt3 + wtElems;    // P*128 bf16 intermediate

    transpose_w<<<TAPS, 256, 0, stream>>>(W1a, wt0);
    transpose_w<<<TAPS, 256, 0, stream>>>(W1b, wt1);
    transpose_w<<<TAPS, 256, 0, stream>>>(W2a, wt2);
    transpose_w<<<TAPS, 256, 0, stream>>>(W2b, wt3);
    split_feats<<<(P * N + 255) / 256, 256, 0, stream>>>(feats, out_hl, P * N);

    const int blocks = (P + MT - 1) / MT;
    conv_k<0><<<blocks, 256, 0, stream>>>(out_hl, wt0, b1a, nbr, nullptr, nullptr, hA, nullptr, P);
    conv_k<1><<<blocks, 256, 0, stream>>>(hA, wt1, b1b, nbr, cond, nullptr, out_hl, nullptr, P);
    conv_k<2><<<blocks, 256, 0, stream>>>(out_hl, wt2, b2a, nbr, nullptr, nullptr, hA, nullptr, P);
    conv_k<3><<<blocks, 256, 0, stream>>>(hA, wt3, b2b, nbr, nullptr, feats, nullptr, out, P);
}

// Round 3
// 1116.342 us; speedup vs baseline: 1.1808x; 1.1300x over previous
//
#include <hip/hip_runtime.h>
#include <hip/hip_bf16.h>

// Sparse 3D conv block (4x 27-tap convs, N=64), float32 in/out.
// Round 7: fix staging line-divergence. Rounds 4-6 staged one THREAD per row ->
//   64 distinct cache lines per wave-load (10,240 line-cy/CU/tap = the hidden
//   ~10k cy/tap rocprof gap). Now 16 consecutive LANES cover one 256B row and
//   staging is global_load_lds_dwordx4 (linear LDS dest + per-lane pre-swizzled
//   SOURCE, rule-21 both-sides involution; B source made fully linear by
//   pre-swizzling Wt at transpose time). Missing neighbors -> 256B zero page.
//   - MT=256, wave tile 64x64 (Mt=2 x Nt=2), reads/MFMA 0.67
//   - split-bf16 emulated f32 (hi*hi + hi*lo + lo*hi), numerics unchanged
//   - LDS rows 256B = 16 slots of 16B; slot s of row r holds half s>>3,
//     granule (s&7)^(r&7); read swizzle unchanged from round 6
//   - LDS 80KB -> 2 blocks/CU; no ds_write instructions at all

#define N 64
#define TAPS 27
#define MT 256

typedef unsigned short u16;
typedef __attribute__((ext_vector_type(8))) short short8;
typedef __attribute__((ext_vector_type(16))) float floatx16;

__device__ __forceinline__ float bf2f(u16 v) {
    union { unsigned u; float f; } c;
    c.u = ((unsigned)v) << 16;
    return c.f;
}
__device__ __forceinline__ u16 f2bf(float f) {
    __hip_bfloat16 h = __float2bfloat16(f);  // RNE
    u16 r;
    __builtin_memcpy(&r, &h, 2);
    return r;
}
__device__ __forceinline__ void split2(float x, u16& hi, u16& lo) {
    hi = f2bf(x);
    lo = f2bf(x - bf2f(hi));
}

// async 16B global -> LDS (DMA; LDS dest = wave-uniform base + lane*16)
__device__ __forceinline__ void async16(u16* lds, const u16* g) {
    __builtin_amdgcn_global_load_lds(
        (const __attribute__((address_space(1))) unsigned int*)g,
        (__attribute__((address_space(3))) unsigned int*)lds, 16, 0, 0);
}

__global__ void zero_zp(u16* zp) { zp[threadIdx.x] = 0; }

// feats f32 [P][64] -> hl bf16 [P][128] (row = hi[0:64] || lo[64:128])
__global__ void split_feats(const float* __restrict__ x, u16* __restrict__ hl, int n) {
    int i = blockIdx.x * 256 + threadIdx.x;
    if (i >= n) return;
    int p = i >> 6, c = i & 63;
    u16 h, l;
    split2(x[i], h, l);
    hl[(size_t)p * 128 + c] = h;
    hl[(size_t)p * 128 + 64 + c] = l;
}

// W f32 [27][64][64] (k,i,j) -> Wt bf16 [27][64][128], PRE-SWIZZLED per row j:
//   slot s (16B granules): hi of input-chans (s^ (j&7))*8..+7 at s in 0..7,
//   lo at s in 8..15. So a linear 256B read of row j is already in LDS slot order.
__global__ void transpose_w(const float* __restrict__ W, u16* __restrict__ Wt) {
    const float* src = W + blockIdx.x * (N * N);
    u16* dst = Wt + blockIdx.x * (N * 128);
    int t = threadIdx.x;
#pragma unroll
    for (int m = 0; m < 16; ++m) {
        int e = t + m * 256;
        int i = e >> 6;   // input channel
        int j = e & 63;   // output channel (row)
        u16 h, l;
        split2(src[e], h, l);
        int x = (((i >> 3) ^ (j & 7)) * 8) + (i & 7);
        dst[j * 128 + x] = h;        // hi slots 0..7
        dst[j * 128 + 64 + x] = l;   // lo slots 8..15
    }
}

// MODE: 0/2 = relu -> hl out; 1 = FiLM -> hl out; 3 = relu + residual -> f32 out
template <int MODE>
__global__ __launch_bounds__(256, 2) void conv_k(
    const u16* __restrict__ Xhl, const u16* __restrict__ Wt,
    const float* __restrict__ bias, const int* __restrict__ nbr,
    const float* __restrict__ cond, const float* __restrict__ resid,
    const u16* __restrict__ zp,
    u16* __restrict__ out_hl, float* __restrict__ out_f32, int P) {
    __shared__ __align__(16) u16 As[MT * 128];  // 64 KB: 256 rows x 16 swizzled 16B slots
    __shared__ __align__(16) u16 Bs[N * 128];   // 16 KB: 64 rows x 16 swizzled 16B slots

    const int tid = threadIdx.x;
    const int pbase = blockIdx.x * MT;

    // compute roles: wave w -> rows [w*64, w*64+64) x all 64 cols
    const int w = tid >> 6;
    const int lane = tid & 63;
    const int cn = lane & 31;     // m-row / n-col within 32x32 tile
    const int kh = lane >> 5;     // K half (8-elem group)
    const int rowA0 = w * 64 + cn;

    // staging roles: 16 lanes per row; instr i covers 4 rows (w*64+i*4 ..+3)
    const int lrow = lane >> 4;   // row within instruction 0..3
    const int lslot = lane & 15;  // dest slot (16B granule)
    // source swizzle offsets (u16 units) for even/odd i: row&7 = (i&1)*4 + lrow
    const int swzE = (lslot >> 3) * 64 + (((lslot & 7) ^ lrow) * 8);
    const int swzO = (lslot >> 3) * 64 + (((lslot & 7) ^ (4 + lrow)) * 8);

    floatx16 acc00, acc01, acc10, acc11;
#pragma unroll
    for (int i = 0; i < 16; ++i) { acc00[i] = 0.f; acc01[i] = 0.f; acc10[i] = 0.f; acc11[i] = 0.f; }

    for (int k = 0; k < TAPS; ++k) {
        if (k) __syncthreads();  // previous tap's frag reads complete

        // ---- phase 1: per-lane neighbor indices for this tap (L1-hot broadcast)
        int ii[16];
#pragma unroll
        for (int i = 0; i < 16; ++i) {
            const int pr = pbase + w * 64 + i * 4 + lrow;
            const int pc = (pr < P) ? pr : (P - 1);
            int v = nbr[(size_t)pc * TAPS + k];
            ii[i] = (pr < P) ? v : -1;
        }
        // ---- phase 2: A staging, 16 async 1KB DMAs (4 gathered rows each)
#pragma unroll
        for (int i = 0; i < 16; ++i) {
            const u16* s = (ii[i] >= 0)
                ? Xhl + (size_t)ii[i] * 128 + ((i & 1) ? swzO : swzE)
                : zp + lslot * 8;
            async16(&As[(w * 64 + i * 4) * 128], s);
        }
        // ---- B staging: 4 async 1KB DMAs, fully linear source (pre-swizzled Wt)
        {
            const u16* wk = Wt + ((size_t)k * N + w * 16) * 128 + lane * 8;
#pragma unroll
            for (int q = 0; q < 4; ++q) {
                async16(&Bs[(w * 16 + q * 4) * 128], wk + q * (4 * 128));
            }
        }

        __syncthreads();  // drains vmcnt -> staged data visible

        // ---- compute tap k: 4 K-chunks, 2x2 MFMA tiles, 3 emulation products
#pragma unroll
        for (int kc = 0; kc < 4; ++kc) {
            const int g = 2 * kc + kh;
            const int sw = (g ^ (cn & 7)) * 8;
            const short8 a_h0 = *reinterpret_cast<const short8*>(&As[rowA0 * 128 + sw]);
            const short8 a_l0 = *reinterpret_cast<const short8*>(&As[rowA0 * 128 + 64 + sw]);
            const short8 a_h1 = *reinterpret_cast<const short8*>(&As[(rowA0 + 32) * 128 + sw]);
            const short8 a_l1 = *reinterpret_cast<const short8*>(&As[(rowA0 + 32) * 128 + 64 + sw]);
            const short8 b_h0 = *reinterpret_cast<const short8*>(&Bs[cn * 128 + sw]);
            const short8 b_l0 = *reinterpret_cast<const short8*>(&Bs[cn * 128 + 64 + sw]);
            const short8 b_h1 = *reinterpret_cast<const short8*>(&Bs[(cn + 32) * 128 + sw]);
            const short8 b_l1 = *reinterpret_cast<const short8*>(&Bs[(cn + 32) * 128 + 64 + sw]);

            acc00 = __builtin_amdgcn_mfma_f32_32x32x16_bf16(a_h0, b_h0, acc00, 0, 0, 0);
            acc00 = __builtin_amdgcn_mfma_f32_32x32x16_bf16(a_h0, b_l0, acc00, 0, 0, 0);
            acc00 = __builtin_amdgcn_mfma_f32_32x32x16_bf16(a_l0, b_h0, acc00, 0, 0, 0);

            acc01 = __builtin_amdgcn_mfma_f32_32x32x16_bf16(a_h0, b_h1, acc01, 0, 0, 0);
            acc01 = __builtin_amdgcn_mfma_f32_32x32x16_bf16(a_h0, b_l1, acc01, 0, 0, 0);
            acc01 = __builtin_amdgcn_mfma_f32_32x32x16_bf16(a_l0, b_h1, acc01, 0, 0, 0);

            acc10 = __builtin_amdgcn_mfma_f32_32x32x16_bf16(a_h1, b_h0, acc10, 0, 0, 0);
            acc10 = __builtin_amdgcn_mfma_f32_32x32x16_bf16(a_h1, b_l0, acc10, 0, 0, 0);
            acc10 = __builtin_amdgcn_mfma_f32_32x32x16_bf16(a_l1, b_h0, acc10, 0, 0, 0);

            acc11 = __builtin_amdgcn_mfma_f32_32x32x16_bf16(a_h1, b_h1, acc11, 0, 0, 0);
            acc11 = __builtin_amdgcn_mfma_f32_32x32x16_bf16(a_h1, b_l1, acc11, 0, 0, 0);
            acc11 = __builtin_amdgcn_mfma_f32_32x32x16_bf16(a_l1, b_h1, acc11, 0, 0, 0);
        }
    }

    // ---- epilogue: 32x32 C/D layout col=lane&31, row=(reg&3)+8*(reg>>2)+4*kh
    auto epi = [&](const floatx16& a, int mt, int nt) {
        const int j = nt * 32 + cn;
        const float bj = bias[j];
#pragma unroll
        for (int reg = 0; reg < 16; ++reg) {
            const int row = (reg & 3) + 8 * (reg >> 2) + 4 * kh;
            const int p = pbase + w * 64 + mt * 32 + row;
            if (p < P) {
                float o = a[reg] + bj;
                if (MODE == 0 || MODE == 2) o = fmaxf(o, 0.f);
                if (MODE == 1) {
                    const float be = cond[(size_t)p * (2 * N) + j];
                    const float ga = cond[(size_t)p * (2 * N) + N + j];
                    o = o * be + ga;
                }
                if (MODE == 3) {
                    o = fmaxf(o, 0.f) + resid[(size_t)p * N + j];
                    out_f32[(size_t)p * N + j] = o;
                } else {
                    u16 h, l;
                    split2(o, h, l);
                    out_hl[(size_t)p * 128 + j] = h;
                    out_hl[(size_t)p * 128 + 64 + j] = l;
                }
            }
        }
    };
    epi(acc00, 0, 0);
    epi(acc01, 0, 1);
    epi(acc10, 1, 0);
    epi(acc11, 1, 1);
}

extern "C" void kernel_launch(void* const* d_in, const int* in_sizes, int n_in,
                              void* d_out, int out_size, void* d_ws, size_t ws_size,
                              hipStream_t stream) {
    const float* feats = (const float*)d_in[0];
    const float* cond  = (const float*)d_in[1];
    const float* W1a   = (const float*)d_in[2];
    const float* b1a   = (const float*)d_in[3];
    const float* W1b   = (const float*)d_in[4];
    const float* b1b   = (const float*)d_in[5];
    const float* W2a   = (const float*)d_in[6];
    const float* b2a   = (const float*)d_in[7];
    const float* W2b   = (const float*)d_in[8];
    const float* b2b   = (const float*)d_in[9];
    const int* nbr     = (const int*)d_in[10];
    float* out = (float*)d_out;
    u16* out_hl = (u16*)d_out;   // d_out doubles as hl scratch (P*128 bf16 == P*64 f32 bytes)

    const int P = in_sizes[0] / N;

    const size_t wtElems = (size_t)TAPS * N * 128;  // 221184 bf16 per conv
    u16* zp  = (u16*)d_ws;       // 128 u16 = 256B zero page
    u16* wt0 = zp + 128;
    u16* wt1 = wt0 + wtElems;
    u16* wt2 = wt1 + wtElems;
    u16* wt3 = wt2 + wtElems;
    u16* hA  = wt3 + wtElems;    // P*128 bf16 intermediate

    zero_zp<<<1, 128, 0, stream>>>(zp);
    transpose_w<<<TAPS, 256, 0, stream>>>(W1a, wt0);
    transpose_w<<<TAPS, 256, 0, stream>>>(W1b, wt1);
    transpose_w<<<TAPS, 256, 0, stream>>>(W2a, wt2);
    transpose_w<<<TAPS, 256, 0, stream>>>(W2b, wt3);
    split_feats<<<(P * N + 255) / 256, 256, 0, stream>>>(feats, out_hl, P * N);

    const int blocks = (P + MT - 1) / MT;
    conv_k<0><<<blocks, 256, 0, stream>>>(out_hl, wt0, b1a, nbr, nullptr, nullptr, zp, hA, nullptr, P);
    conv_k<1><<<blocks, 256, 0, stream>>>(hA, wt1, b1b, nbr, cond, nullptr, zp, out_hl, nullptr, P);
    conv_k<2><<<blocks, 256, 0, stream>>>(out_hl, wt2, b2a, nbr, nullptr, nullptr, zp, hA, nullptr, P);
    conv_k<3><<<blocks, 256, 0, stream>>>(hA, wt3, b2b, nbr, nullptr, feats, zp, nullptr, out, P);
}